// Round 8
// baseline (233.616 us; speedup 1.0000x reference)
//
#include <hip/hip_runtime.h>

// out[m,k] = D*(w-1)*rowsum(t[m]) broadcast over k (K = D = 2048).
//
// Cache-policy quadrant test (single variable vs R7): plain CACHED loads
// + NT stores. Rationale: harness restores d_in right before every timed
// launch, so input is L3-warm (R4 measured FETCH=65 MB of 131 -> 50% L3
// absorption) -- NT loads forfeit that. NT stores keep the 131 MB
// touch-once output from write-allocating into L2/L3 (candidate cause of
// R4 plain/plain's 82 us vs R3 NT/NT's 71 us).
// Structure unchanged from R7: persistent 1024 blocks, 4 rows/wave,
// 2-deep register pipeline, wave-64 butterfly reduction, no LDS.

#define M_ROWS 16384
#define D_COLS 2048
#define F4_PER_ROW (D_COLS / 4)   // 512
#define WAVES_PER_BLOCK 4
#define BLOCK_SIZE (WAVES_PER_BLOCK * 64)
#define GRID_BLOCKS 1024          // 4 blocks/CU, 16 waves/CU resident
#define TOTAL_WAVES (GRID_BLOCKS * WAVES_PER_BLOCK)       // 4096
#define ROWS_PER_WAVE (M_ROWS / TOTAL_WAVES)              // 4

typedef float vf4 __attribute__((ext_vector_type(4)));

__global__ __launch_bounds__(BLOCK_SIZE)
void perm_equiv_persist(const float* __restrict__ t,
                        const float* __restrict__ w,
                        float* __restrict__ out) {
    const int lane  = threadIdx.x & 63;
    const int gwave = blockIdx.x * WAVES_PER_BLOCK + (threadIdx.x >> 6);

    const float scale = (float)D_COLS * (w[0] - 1.0f);

    const vf4* tin  = reinterpret_cast<const vf4*>(t);
    vf4*       oput = reinterpret_cast<vf4*>(out);

    // prologue: prime row 0's loads (plain/cached -> can hit L3-warm input)
    const vf4* p0 = tin + (size_t)gwave * F4_PER_ROW;
    vf4 cur[8];
    #pragma unroll
    for (int j = 0; j < 8; ++j)
        cur[j] = p0[j * 64 + lane];

    #pragma unroll
    for (int r = 0; r < ROWS_PER_WAVE; ++r) {
        const int row = gwave + r * TOTAL_WAVES;

        // issue next row's loads BEFORE consuming current row
        vf4 nxt[8];
        if (r + 1 < ROWS_PER_WAVE) {
            const vf4* pn = tin + (size_t)(row + TOTAL_WAVES) * F4_PER_ROW;
            #pragma unroll
            for (int j = 0; j < 8; ++j)
                nxt[j] = pn[j * 64 + lane];
        }

        float s = 0.0f;
        #pragma unroll
        for (int j = 0; j < 8; ++j)
            s += (cur[j].x + cur[j].y) + (cur[j].z + cur[j].w);

        // wave-64 butterfly: every lane ends with the full row sum.
        #pragma unroll
        for (int m = 32; m > 0; m >>= 1)
            s += __shfl_xor(s, m, 64);

        const float val = scale * s;
        vf4 v4;
        v4.x = val; v4.y = val; v4.z = val; v4.w = val;

        // NT stores: touch-once output, keep it out of L2/L3.
        vf4* orow = oput + (size_t)row * F4_PER_ROW;
        #pragma unroll
        for (int j = 0; j < 8; ++j)
            __builtin_nontemporal_store(v4, orow + j * 64 + lane);

        if (r + 1 < ROWS_PER_WAVE) {
            #pragma unroll
            for (int j = 0; j < 8; ++j)
                cur[j] = nxt[j];
        }
    }
}

extern "C" void kernel_launch(void* const* d_in, const int* in_sizes, int n_in,
                              void* d_out, int out_size, void* d_ws, size_t ws_size,
                              hipStream_t stream) {
    const float* t = (const float*)d_in[0];
    const float* w = (const float*)d_in[1];
    float* out = (float*)d_out;
    perm_equiv_persist<<<GRID_BLOCKS, BLOCK_SIZE, 0, stream>>>(t, w, out);
}

// Round 9
// 221.414 us; speedup vs baseline: 1.0551x; 1.0551x over previous
//
#include <hip/hip_runtime.h>

// out[m,k] = D*(w-1)*rowsum(t[m]) broadcast over k (K = D = 2048).
//
// R1-R8 summary: every structure/cache-policy variant lands 71-82 us
// (NT/NT fused best at 71; floor is ~43 us at the 6.3 TB/s copy ceiling).
// Writes are proven fine (harness fills: 6.7 TB/s @ 9% occupancy). The
// wall is the read stream's in-flight-bytes x latency product. This round:
// maximize per-wave read depth -- 4 rows/wave, ALL 32 NT dwordx4 loads
// issued up front (32 KB in flight/wave, 4x R3's depth), contiguous 32 KB
// per wave for DRAM page locality. Consumption walks a descending vmcnt
// ladder (24->16->8->0); NT stores overlap remaining loads. ~128 data
// VGPRs -> ~12 waves/CU -> ~384 KB nominal in-flight/CU (1.5-3x prior).

#define M_ROWS 16384
#define D_COLS 2048
#define F4_PER_ROW (D_COLS / 4)   // 512
#define WAVES_PER_BLOCK 4
#define BLOCK_SIZE (WAVES_PER_BLOCK * 64)
#define ROWS_PER_WAVE 4
#define GRID_BLOCKS (M_ROWS / (WAVES_PER_BLOCK * ROWS_PER_WAVE))  // 1024

typedef float vf4 __attribute__((ext_vector_type(4)));

__global__ __launch_bounds__(BLOCK_SIZE)
void perm_equiv_deep(const float* __restrict__ t,
                     const float* __restrict__ w,
                     float* __restrict__ out) {
    const int lane  = threadIdx.x & 63;
    const int gwave = blockIdx.x * WAVES_PER_BLOCK + (threadIdx.x >> 6);
    const int row0  = gwave * ROWS_PER_WAVE;   // 4 contiguous rows per wave

    const float scale = (float)D_COLS * (w[0] - 1.0f);

    const vf4* base = reinterpret_cast<const vf4*>(t) + (size_t)row0 * F4_PER_ROW;

    // Issue ALL 32 nontemporal loads up front: 32 KB in flight per wave.
    vf4 v[ROWS_PER_WAVE][8];
    #pragma unroll
    for (int r = 0; r < ROWS_PER_WAVE; ++r) {
        const vf4* p = base + (size_t)r * F4_PER_ROW;
        #pragma unroll
        for (int j = 0; j < 8; ++j)
            v[r][j] = __builtin_nontemporal_load(p + j * 64 + lane);
    }

    // Consume rows in issue order: compiler waits at vmcnt(24/16/8/0),
    // so later rows' loads stay in flight while earlier rows reduce+store.
    #pragma unroll
    for (int r = 0; r < ROWS_PER_WAVE; ++r) {
        float s = 0.0f;
        #pragma unroll
        for (int j = 0; j < 8; ++j)
            s += (v[r][j].x + v[r][j].y) + (v[r][j].z + v[r][j].w);

        // wave-64 butterfly: every lane ends with the full row sum.
        #pragma unroll
        for (int m = 32; m > 0; m >>= 1)
            s += __shfl_xor(s, m, 64);

        const float val = scale * s;
        vf4 v4;
        v4.x = val; v4.y = val; v4.z = val; v4.w = val;

        vf4* orow = reinterpret_cast<vf4*>(out) + (size_t)(row0 + r) * F4_PER_ROW;
        #pragma unroll
        for (int j = 0; j < 8; ++j)
            __builtin_nontemporal_store(v4, orow + j * 64 + lane);
    }
}

extern "C" void kernel_launch(void* const* d_in, const int* in_sizes, int n_in,
                              void* d_out, int out_size, void* d_ws, size_t ws_size,
                              hipStream_t stream) {
    const float* t = (const float*)d_in[0];
    const float* w = (const float*)d_in[1];
    float* out = (float*)d_out;
    perm_equiv_deep<<<GRID_BLOCKS, BLOCK_SIZE, 0, stream>>>(t, w, out);
}